// Round 3
// baseline (248.579 us; speedup 1.0000x reference)
//
#include <hip/hip_runtime.h>
#include <hip/hip_bf16.h>

#define N_NODES 50000
#define N_EDGES 800000
#define N_GRAPHS 8
#define MAXDEG 64
#define NRANGE 4
#define NCHUNK 64
#define RSZ (N_NODES / NRANGE)      // 12500 nodes per range
#define CHE (N_EDGES / NCHUNK)      // 12500 edges per chunk
#define SENT 50000                  // sentinel source row (zeroed in prep)
#define PLANE_ROWS 50048
#define PLANE_BYTES ((size_t)PLANE_ROWS * 64)

typedef __attribute__((ext_vector_type(8))) short short8;
typedef __attribute__((ext_vector_type(4))) float floatx4;
typedef __attribute__((ext_vector_type(2))) float floatx2;

static __device__ __forceinline__ ushort f2b(float f) {
    union { float f; unsigned u; } v; v.f = f;
    return (ushort)((v.u + 0x7FFF + ((v.u >> 16) & 1)) >> 16);  // RNE
}
static __device__ __forceinline__ float b2f(unsigned u) {
    union { unsigned u; float f; } v; v.u = u << 16;
    return v.f;
}

// ================= K1: prep = count ∪ wt_convert ∪ bound ∪ slot-fill ===========
// blocks [0,256): per-(range,chunk) LDS histograms (LDS privatization — device
//                 atomics cost 73 µs, measured round 1)
// blocks [256,272): W1/W2 fp32 [k][c] -> Wt bf16 [c][k]; block 256 also zeroes
//                   the sentinel row (SENT) of both fp8 planes
// blocks [272,321): graph boundary detection (gid sorted)
// blocks [321,712): fill slot[] with SENT so SpMM gathers are predication-free
__global__ __launch_bounds__(1024) void prep_kernel(
    const int* __restrict__ src, const int* __restrict__ dst,
    const float* __restrict__ W1, const float* __restrict__ W2,
    const int* __restrict__ gid,
    ushort* __restrict__ counts_in, ushort* __restrict__ counts_out,
    ushort* __restrict__ Wt1, ushort* __restrict__ Wt2,
    int* __restrict__ start,
    unsigned char* __restrict__ hA, uint4* __restrict__ slot_fill)
{
    int b = blockIdx.x, t = threadIdx.x;
    if (b < 256) {
        __shared__ unsigned h[RSZ];   // [0,RSZ/2) in-hist, [RSZ/2,RSZ) out-hist (packed 2x16)
        int c = b & (NCHUNK - 1), r = b >> 6;
        int lo = r * RSZ;
        for (int j = t; j < RSZ; j += 1024) h[j] = 0;
        __syncthreads();
        int ebeg = c * CHE, eend = ebeg + CHE;
        for (int i = ebeg + t; i < eend; i += 1024) {
            int s = src[i], d = dst[i];
            unsigned ds = (unsigned)(d - lo);
            if (ds < RSZ) atomicAdd(&h[ds >> 1], 1u << ((ds & 1) * 16));
            unsigned ss = (unsigned)(s - lo);
            if (ss < RSZ) atomicAdd(&h[(RSZ / 2) + (ss >> 1)], 1u << ((ss & 1) * 16));
        }
        __syncthreads();
        unsigned* ci = (unsigned*)(counts_in  + (size_t)c * N_NODES + lo);
        unsigned* co = (unsigned*)(counts_out + (size_t)c * N_NODES + lo);
        for (int j = t; j < RSZ / 2; j += 1024) {
            ci[j] = h[j];
            co[j] = h[(RSZ / 2) + j];
        }
    } else if (b < 272) {
        int i = (b - 256) * 1024 + t;          // 16384 elems
        int c = i >> 7, k = i & 127;
        Wt1[i] = f2b(W1[k * 128 + c]);
        Wt2[i] = f2b(W2[k * 128 + c]);
        if (b == 256) {                        // zero sentinel rows (64 B each plane)
            if (t < 16)
                ((unsigned*)(hA + (size_t)SENT * 64))[t] = 0u;
            else if (t < 32)
                ((unsigned*)(hA + PLANE_BYTES + (size_t)SENT * 64))[t - 16] = 0u;
        }
    } else if (b < 321) {
        int i = (b - 272) * 1024 + t;
        if (i < N_NODES) {
            int g = gid[i];
            int gp = (i == 0) ? -1 : gid[i - 1];
            for (int k = gp + 1; k <= g; ++k) start[k] = i;    // unique writer per k
            if (i == N_NODES - 1)
                for (int k = g + 1; k <= N_GRAPHS; ++k) start[k] = N_NODES;
        }
    } else {
        int i = (b - 321) * 1024 + t;          // 400000 uint4 = 6.4 MB of SENT
        if (i < (N_NODES * MAXDEG * 2) / 16)
            slot_fill[i] = make_uint4(0xC350C350u, 0xC350C350u, 0xC350C350u, 0xC350C350u);
    }
}

// ================= K2: scan chunk counts -> degrees, norms, slot bases ==========
__global__ __launch_bounds__(256) void scan_kernel(
    const ushort* __restrict__ counts_in, const ushort* __restrict__ counts_out,
    ushort* __restrict__ base, int* __restrict__ in_deg,
    float* __restrict__ ns, float* __restrict__ nd)
{
    int v = blockIdx.x * 256 + threadIdx.x;
    if (v >= N_NODES) return;
    unsigned od = 0;
    #pragma unroll 8
    for (int c = 0; c < NCHUNK; ++c) od += counts_out[(size_t)c * N_NODES + v];
    unsigned run = 0;
    #pragma unroll 8
    for (int c = 0; c < NCHUNK; ++c) {
        base[(size_t)c * N_NODES + v] = (ushort)run;
        run += counts_in[(size_t)c * N_NODES + v];
    }
    in_deg[v] = (int)run;
    ns[v] = rsqrtf(fmaxf((float)od, 1.f));
    nd[v] = rsqrtf(fmaxf((float)run, 1.f));
}

// ================= K3: scatter into ELL slots using LDS-seeded bases ===========
__global__ __launch_bounds__(1024) void scatter_kernel(
    const int* __restrict__ src, const int* __restrict__ dst,
    const ushort* __restrict__ base, ushort* __restrict__ slot)
{
    __shared__ unsigned h[RSZ / 2];   // packed 2x16 running positions
    int t = threadIdx.x;
    int c = blockIdx.x & (NCHUNK - 1), r = blockIdx.x >> 6;
    int lo = r * RSZ;
    const unsigned* bp = (const unsigned*)(base + (size_t)c * N_NODES + lo);
    for (int j = t; j < RSZ / 2; j += 1024) h[j] = bp[j];
    __syncthreads();
    int ebeg = c * CHE, eend = ebeg + CHE;
    for (int i = ebeg + t; i < eend; i += 1024) {
        int d = dst[i];
        unsigned ds = (unsigned)(d - lo);
        if (ds < RSZ) {
            int sh = (ds & 1) * 16;
            unsigned old = atomicAdd(&h[ds >> 1], 1u << sh);
            unsigned pos = (old >> sh) & 0xffff;
            if (pos < MAXDEG) slot[(size_t)d * MAXDEG + pos] = (ushort)src[i];
        }
    }
}

// ================= K4/K6: MFMA GEMM, whole W in 128 VGPRs, 1 tile/wave =========
// Operand-swapped mfma(B,a): D transposed -> lane (m,q) holds, per cb,
// row = tile*16+m with 4 CONSECUTIVE cols cb*16+q*4..+3 -> one dword fp8 store.
// Output written as TWO 64-col planes (3.2 MB each, < 4 MB per-XCD L2) so the
// SpMM gather working set is L2-resident per pass.
template<int FP32_IN>
__global__ __launch_bounds__(256, 2) void mfma_gemm_kernel(
    const void* __restrict__ Xv, const float* __restrict__ scale,
    const ushort* __restrict__ Wt, unsigned char* __restrict__ Y)
{
    int t = threadIdx.x;
    int wv = t >> 6, lane = t & 63;
    int m = lane & 15, q = lane >> 4;
    int tile = blockIdx.x * 4 + wv;
    if (tile >= (N_NODES >> 4)) return;         // 3125 tiles (exact)

    short8 B[8][4];
    #pragma unroll
    for (int cb = 0; cb < 8; ++cb)
        #pragma unroll
        for (int kb = 0; kb < 4; ++kb)
            B[cb][kb] = *(const short8*)&Wt[(size_t)(cb * 16 + m) * 128 + kb * 32 + q * 8];

    int row = tile * 16 + m;
    short8 a[4];
    if (FP32_IN) {
        const float* X = (const float*)Xv;
        float s = scale[row];
        #pragma unroll
        for (int kb = 0; kb < 4; ++kb) {
            const float* p = X + (size_t)row * 128 + kb * 32 + q * 8;
            float4 f0 = *(const float4*)p;
            float4 f1 = *(const float4*)(p + 4);
            short8 av;
            av[0] = (short)f2b(f0.x * s); av[1] = (short)f2b(f0.y * s);
            av[2] = (short)f2b(f0.z * s); av[3] = (short)f2b(f0.w * s);
            av[4] = (short)f2b(f1.x * s); av[5] = (short)f2b(f1.y * s);
            av[6] = (short)f2b(f1.z * s); av[7] = (short)f2b(f1.w * s);
            a[kb] = av;
        }
    } else {
        const ushort* X = (const ushort*)Xv;
        #pragma unroll
        for (int kb = 0; kb < 4; ++kb)
            a[kb] = *(const short8*)(X + (size_t)row * 128 + kb * 32 + q * 8);
    }
    floatx4 acc[8] = {};
    #pragma unroll
    for (int cb = 0; cb < 8; ++cb)
        #pragma unroll
        for (int kb = 0; kb < 4; ++kb)
            acc[cb] = __builtin_amdgcn_mfma_f32_16x16x32_bf16(B[cb][kb], a[kb], acc[cb], 0, 0, 0);

    // swapped D layout: out row = tile*16 + m, cols = cb*16 + q*4 + {0..3}
    unsigned char* p0 = Y + (size_t)row * 64;                   // cols 0..63
    unsigned char* p1 = Y + PLANE_BYTES + (size_t)row * 64;     // cols 64..127
    #pragma unroll
    for (int cb = 0; cb < 8; ++cb) {
        int lo = __builtin_amdgcn_cvt_pk_fp8_f32(acc[cb][0], acc[cb][1], 0, false);
        int pk = __builtin_amdgcn_cvt_pk_fp8_f32(acc[cb][2], acc[cb][3], lo, true);
        unsigned char* yp = (cb < 4) ? p0 : p1;
        *(unsigned*)(yp + (cb & 3) * 16 + q * 4) = (unsigned)pk;
    }
}

// ================= K5/K7: SpMM over ONE 64-col plane, one wave per dst node ====
// 8 lanes x 8 B per source row -> 8 rows (one 64-B line each) per vmem instr.
// All ceil(cnt/8) gathers issued upfront (sentinel-safe slots, wave-uniform
// guards) -> up to 8 loads in flight per wave. Plane = 3.2 MB -> L2-resident.
__global__ __launch_bounds__(256) void spmm_fp8_kernel(
    const unsigned char* __restrict__ Hp, const int* __restrict__ in_deg,
    const ushort* __restrict__ slot, const float* __restrict__ norm_dst,
    const float* __restrict__ norm_src, const float* __restrict__ bias,
    ushort* __restrict__ Y, int colbase, int relu_scale)
{
    int w = (blockIdx.x * blockDim.x + threadIdx.x) >> 6;
    int lane = threadIdx.x & 63;
    if (w >= N_NODES) return;
    int cnt = min(in_deg[w], MAXDEG);
    int jmax = (cnt + 7) >> 3;                 // wave-uniform
    const ushort* lst = slot + (size_t)w * MAXDEG;
    int rg = lane >> 3;            // row-group 0..7
    int c8 = (lane & 7) * 8;       // fp8 col byte base within the 64-B row
    int myslot = lst[lane];        // whole slot row staged across the wave
    uint2 v[8];
    #pragma unroll
    for (int j = 0; j < 8; ++j)
        if (j < jmax) {
            int s = __shfl(myslot, j * 8 + rg, 64);
            v[j] = *(const uint2*)&Hp[(size_t)s * 64 + c8];
        }
    float acc[8] = {};
    #pragma unroll
    for (int j = 0; j < 8; ++j)
        if (j < jmax) {
            floatx2 p01 = __builtin_amdgcn_cvt_pk_f32_fp8((int)v[j].x, false);
            floatx2 p23 = __builtin_amdgcn_cvt_pk_f32_fp8((int)v[j].x, true);
            floatx2 p45 = __builtin_amdgcn_cvt_pk_f32_fp8((int)v[j].y, false);
            floatx2 p67 = __builtin_amdgcn_cvt_pk_f32_fp8((int)v[j].y, true);
            acc[0] += p01.x; acc[1] += p01.y;
            acc[2] += p23.x; acc[3] += p23.y;
            acc[4] += p45.x; acc[5] += p45.y;
            acc[6] += p67.x; acc[7] += p67.y;
        }
    #pragma unroll
    for (int j = 0; j < 8; ++j) {
        acc[j] += __shfl_xor(acc[j], 8, 64);
        acc[j] += __shfl_xor(acc[j], 16, 64);
        acc[j] += __shfl_xor(acc[j], 32, 64);
    }
    float ndv = norm_dst[w];
    int col = colbase + c8;        // output col base (c8 doubles as col offset)
    float4 b0 = *(const float4*)&bias[col];
    float4 b1 = *(const float4*)&bias[col + 4];
    float r[8];
    r[0] = acc[0] * ndv + b0.x; r[1] = acc[1] * ndv + b0.y;
    r[2] = acc[2] * ndv + b0.z; r[3] = acc[3] * ndv + b0.w;
    r[4] = acc[4] * ndv + b1.x; r[5] = acc[5] * ndv + b1.y;
    r[6] = acc[6] * ndv + b1.z; r[7] = acc[7] * ndv + b1.w;
    if (relu_scale) {
        float nsv = norm_src[w];
        #pragma unroll
        for (int j = 0; j < 8; ++j) r[j] = fmaxf(r[j], 0.f) * nsv;
    }
    if (lane < 8) {
        uint4 o;
        o.x = (unsigned)f2b(r[0]) | ((unsigned)f2b(r[1]) << 16);
        o.y = (unsigned)f2b(r[2]) | ((unsigned)f2b(r[3]) << 16);
        o.z = (unsigned)f2b(r[4]) | ((unsigned)f2b(r[5]) << 16);
        o.w = (unsigned)f2b(r[6]) | ((unsigned)f2b(r[7]) << 16);
        *(uint4*)&Y[(size_t)w * 128 + col] = o;
    }
}

// ================= K8: pooling -> per-block partials (no atomics, no memset) ====
__global__ __launch_bounds__(256) void pool_kernel(
    const ushort* __restrict__ H, const int* __restrict__ start,
    float* __restrict__ part)
{
    __shared__ float red[128];
    int t = threadIdx.x;
    int g = blockIdx.x >> 5, j = blockIdx.x & 31;
    int beg0 = start[g], len = start[g + 1] - beg0;
    int sbeg = beg0 + (int)(((long long)len * j) >> 5);
    int send = beg0 + (int)(((long long)len * (j + 1)) >> 5);
    int wv = t >> 6, lane = t & 63;
    int rg = lane >> 4;
    int c8 = (lane & 15) * 8;
    float acc[8] = {};
    for (int v = sbeg + wv * 4 + rg; v < send; v += 16) {
        uint4 u = *(const uint4*)&H[(size_t)v * 128 + c8];
        acc[0] += b2f(u.x & 0xffff); acc[1] += b2f(u.x >> 16);
        acc[2] += b2f(u.y & 0xffff); acc[3] += b2f(u.y >> 16);
        acc[4] += b2f(u.z & 0xffff); acc[5] += b2f(u.z >> 16);
        acc[6] += b2f(u.w & 0xffff); acc[7] += b2f(u.w >> 16);
    }
    #pragma unroll
    for (int k = 0; k < 8; ++k) {
        acc[k] += __shfl_xor(acc[k], 16, 64);
        acc[k] += __shfl_xor(acc[k], 32, 64);
    }
    if (t < 128) red[t] = 0.f;
    __syncthreads();
    if (lane < 16) {
        #pragma unroll
        for (int k = 0; k < 8; ++k) atomicAdd(&red[c8 + k], acc[k]);
    }
    __syncthreads();
    if (t < 128) part[(size_t)blockIdx.x * 128 + t] = red[t];
}

// ================= K9: head: out[8,64] = (Σpart/cnt) @ Wl + bl ==================
__global__ __launch_bounds__(512) void head_kernel(
    const float* __restrict__ part, const int* __restrict__ start,
    const float* __restrict__ Wl, const float* __restrict__ bl,
    float* __restrict__ out)
{
    __shared__ float means[N_GRAPHS * 128];
    int t = threadIdx.x;
    for (int i = t; i < N_GRAPHS * 128; i += 512) {
        int g = i >> 7, k = i & 127;
        float s = 0.f;
        #pragma unroll 8
        for (int j = 0; j < 32; ++j) s += part[(size_t)(g * 32 + j) * 128 + k];
        float cnt = (float)(start[g + 1] - start[g]);
        means[i] = s / fmaxf(cnt, 1.f);
    }
    __syncthreads();
    int g = t >> 6, c = t & 63;
    float acc = bl[c];
    #pragma unroll 8
    for (int k = 0; k < 128; ++k)
        acc = fmaf(means[g * 128 + k], Wl[k * 64 + c], acc);
    out[g * 64 + c] = acc;
}

extern "C" void kernel_launch(void* const* d_in, const int* in_sizes, int n_in,
                              void* d_out, int out_size, void* d_ws, size_t ws_size,
                              hipStream_t stream) {
    const float* x   = (const float*)d_in[0];
    const float* W1  = (const float*)d_in[1];
    const float* b1  = (const float*)d_in[2];
    const float* W2  = (const float*)d_in[3];
    const float* b2  = (const float*)d_in[4];
    const float* Wl  = (const float*)d_in[5];
    const float* bl  = (const float*)d_in[6];
    const int*   src = (const int*)d_in[7];
    const int*   dst = (const int*)d_in[8];
    const int*   gid = (const int*)d_in[9];

    const int n = N_NODES;

    char* ws = (char*)d_ws;
    size_t off = 0;
    auto alloc = [&](size_t bytes) { size_t o = off; off += (bytes + 255) & ~(size_t)255; return o; };
    unsigned char* hA = (unsigned char*)(ws + alloc(2 * PLANE_BYTES));       // gemm out (fp8, 2 planes)
    ushort* hB        = (ushort*)(ws + alloc((size_t)n * 128 * 2));          // spmm out (bf16)
    ushort* slot      = (ushort*)(ws + alloc((size_t)n * MAXDEG * 2));       // ELL src lists
    ushort* counts_in = (ushort*)(ws + alloc((size_t)NCHUNK * n * 2));
    ushort* counts_out= (ushort*)(ws + alloc((size_t)NCHUNK * n * 2));
    ushort* basev     = (ushort*)(ws + alloc((size_t)NCHUNK * n * 2));
    float* norm_src   = (float*) (ws + alloc((size_t)n * 4));
    float* norm_dst   = (float*) (ws + alloc((size_t)n * 4));
    int*   in_deg     = (int*)   (ws + alloc((size_t)n * 4));
    int*   startb     = (int*)   (ws + alloc((size_t)(N_GRAPHS + 1) * 4));
    ushort* Wt1       = (ushort*)(ws + alloc((size_t)128 * 128 * 2));
    ushort* Wt2       = (ushort*)(ws + alloc((size_t)128 * 128 * 2));
    float* part       = (float*) (ws + alloc((size_t)N_GRAPHS * 32 * 128 * 4));

    const unsigned char* plane0 = hA;
    const unsigned char* plane1 = hA + PLANE_BYTES;

    int spmm_blocks = (n + 3) / 4;
    int gemm_blocks = ((n >> 4) + 3) / 4;       // 1 tile/wave, 4 waves/block
    int fill_blocks = ((N_NODES * MAXDEG * 2) / 16 + 1023) / 1024;   // 391

    // K1: count ∪ wt_convert ∪ bounds ∪ slot-fill
    prep_kernel<<<321 + fill_blocks, 1024, 0, stream>>>(
        src, dst, W1, W2, gid, counts_in, counts_out, Wt1, Wt2, startb,
        hA, (uint4*)slot);
    // K2: scan
    scan_kernel<<<(n + 255) / 256, 256, 0, stream>>>(counts_in, counts_out, basev,
                                                     in_deg, norm_src, norm_dst);
    // K3: scatter (LDS-seeded bases)
    scatter_kernel<<<NRANGE * NCHUNK, 1024, 0, stream>>>(src, dst, basev, slot);
    // K4: gemm1  (planes = fp8((x*ns) @ W1))
    mfma_gemm_kernel<1><<<gemm_blocks, 256, 0, stream>>>(x, norm_src, Wt1, hA);
    // K5: spmm1, one plane at a time (L2-resident working set)
    spmm_fp8_kernel<<<spmm_blocks, 256, 0, stream>>>(plane0, in_deg, slot, norm_dst,
                                                     norm_src, b1, hB, 0, 1);
    spmm_fp8_kernel<<<spmm_blocks, 256, 0, stream>>>(plane1, in_deg, slot, norm_dst,
                                                     norm_src, b1, hB, 64, 1);
    // K6: gemm2  (planes = fp8(hB @ W2))
    mfma_gemm_kernel<0><<<gemm_blocks, 256, 0, stream>>>(hB, nullptr, Wt2, hA);
    // K7: spmm2
    spmm_fp8_kernel<<<spmm_blocks, 256, 0, stream>>>(plane0, in_deg, slot, norm_dst,
                                                     nullptr, b2, hB, 0, 0);
    spmm_fp8_kernel<<<spmm_blocks, 256, 0, stream>>>(plane1, in_deg, slot, norm_dst,
                                                     nullptr, b2, hB, 64, 0);
    // K8: pool partials
    pool_kernel<<<N_GRAPHS * 32, 256, 0, stream>>>(hB, startb, part);
    // K9: head
    head_kernel<<<1, 512, 0, stream>>>(part, startb, Wl, bl, (float*)d_out);
}

// Round 4
// 228.559 us; speedup vs baseline: 1.0876x; 1.0876x over previous
//
#include <hip/hip_runtime.h>
#include <hip/hip_bf16.h>

#define N_NODES 50000
#define N_EDGES 800000
#define N_GRAPHS 8
#define MAXDEG 64
#define NRANGE 4
#define NCHUNK 64
#define RSZ (N_NODES / NRANGE)      // 12500 nodes per range
#define CHE (N_EDGES / NCHUNK)      // 12500 edges per chunk

typedef __attribute__((ext_vector_type(8))) short short8;
typedef __attribute__((ext_vector_type(4))) float floatx4;
typedef __attribute__((ext_vector_type(2))) float floatx2;

static __device__ __forceinline__ ushort f2b(float f) {
    union { float f; unsigned u; } v; v.f = f;
    return (ushort)((v.u + 0x7FFF + ((v.u >> 16) & 1)) >> 16);  // RNE
}
static __device__ __forceinline__ float b2f(unsigned u) {
    union { unsigned u; float f; } v; v.u = u << 16;
    return v.f;
}

// ================= K1: prep = count ∪ wt_convert ∪ bound (round-0 verbatim) ====
// blocks [0,256): per-(range,chunk) LDS histograms (LDS privatization — device
//                 atomics cost 73 µs, measured round 1)
// blocks [256,272): W1/W2 fp32 [k][c] -> Wt bf16 [c][k]
// blocks [272,321): graph boundary detection (gid sorted)
__global__ __launch_bounds__(1024) void prep_kernel(
    const int* __restrict__ src, const int* __restrict__ dst,
    const float* __restrict__ W1, const float* __restrict__ W2,
    const int* __restrict__ gid,
    ushort* __restrict__ counts_in, ushort* __restrict__ counts_out,
    ushort* __restrict__ Wt1, ushort* __restrict__ Wt2,
    int* __restrict__ start)
{
    int b = blockIdx.x, t = threadIdx.x;
    if (b < 256) {
        __shared__ unsigned h[RSZ];   // [0,RSZ/2) in-hist, [RSZ/2,RSZ) out-hist (packed 2x16)
        int c = b & (NCHUNK - 1), r = b >> 6;
        int lo = r * RSZ;
        for (int j = t; j < RSZ; j += 1024) h[j] = 0;
        __syncthreads();
        int ebeg = c * CHE, eend = ebeg + CHE;
        for (int i = ebeg + t; i < eend; i += 1024) {
            int s = src[i], d = dst[i];
            unsigned ds = (unsigned)(d - lo);
            if (ds < RSZ) atomicAdd(&h[ds >> 1], 1u << ((ds & 1) * 16));
            unsigned ss = (unsigned)(s - lo);
            if (ss < RSZ) atomicAdd(&h[(RSZ / 2) + (ss >> 1)], 1u << ((ss & 1) * 16));
        }
        __syncthreads();
        unsigned* ci = (unsigned*)(counts_in  + (size_t)c * N_NODES + lo);
        unsigned* co = (unsigned*)(counts_out + (size_t)c * N_NODES + lo);
        for (int j = t; j < RSZ / 2; j += 1024) {
            ci[j] = h[j];
            co[j] = h[(RSZ / 2) + j];
        }
    } else if (b < 272) {
        int i = (b - 256) * 1024 + t;          // 16384 elems
        int c = i >> 7, k = i & 127;
        Wt1[i] = f2b(W1[k * 128 + c]);
        Wt2[i] = f2b(W2[k * 128 + c]);
    } else {
        int i = (b - 272) * 1024 + t;
        if (i < N_NODES) {
            int g = gid[i];
            int gp = (i == 0) ? -1 : gid[i - 1];
            for (int k = gp + 1; k <= g; ++k) start[k] = i;    // unique writer per k
            if (i == N_NODES - 1)
                for (int k = g + 1; k <= N_GRAPHS; ++k) start[k] = N_NODES;
        }
    }
}

// ================= K2: scan chunk counts -> degrees, norms, slot bases ==========
__global__ __launch_bounds__(256) void scan_kernel(
    const ushort* __restrict__ counts_in, const ushort* __restrict__ counts_out,
    ushort* __restrict__ base, int* __restrict__ in_deg,
    float* __restrict__ ns, float* __restrict__ nd)
{
    int v = blockIdx.x * 256 + threadIdx.x;
    if (v >= N_NODES) return;
    unsigned od = 0;
    #pragma unroll 8
    for (int c = 0; c < NCHUNK; ++c) od += counts_out[(size_t)c * N_NODES + v];
    unsigned run = 0;
    #pragma unroll 8
    for (int c = 0; c < NCHUNK; ++c) {
        base[(size_t)c * N_NODES + v] = (ushort)run;
        run += counts_in[(size_t)c * N_NODES + v];
    }
    in_deg[v] = (int)run;
    ns[v] = rsqrtf(fmaxf((float)od, 1.f));
    nd[v] = rsqrtf(fmaxf((float)run, 1.f));
}

// ================= K3: scatter into ELL slots using LDS-seeded bases ===========
__global__ __launch_bounds__(1024) void scatter_kernel(
    const int* __restrict__ src, const int* __restrict__ dst,
    const ushort* __restrict__ base, ushort* __restrict__ slot)
{
    __shared__ unsigned h[RSZ / 2];   // packed 2x16 running positions
    int t = threadIdx.x;
    int c = blockIdx.x & (NCHUNK - 1), r = blockIdx.x >> 6;
    int lo = r * RSZ;
    const unsigned* bp = (const unsigned*)(base + (size_t)c * N_NODES + lo);
    for (int j = t; j < RSZ / 2; j += 1024) h[j] = bp[j];
    __syncthreads();
    int ebeg = c * CHE, eend = ebeg + CHE;
    for (int i = ebeg + t; i < eend; i += 1024) {
        int d = dst[i];
        unsigned ds = (unsigned)(d - lo);
        if (ds < RSZ) {
            int sh = (ds & 1) * 16;
            unsigned old = atomicAdd(&h[ds >> 1], 1u << sh);
            unsigned pos = (old >> sh) & 0xffff;
            if (pos < MAXDEG) slot[(size_t)d * MAXDEG + pos] = (ushort)src[i];
        }
    }
}

// ================= K4/K6: MFMA GEMM, whole W in 128 VGPRs, 1 tile/wave =========
// Operand-swapped mfma(B,a): D transposed -> lane (m,q) holds, per cb,
// row = tile*16+m with 4 CONSECUTIVE cols cb*16+q*4..+3 -> one dword fp8 store
// (verified correct in rounds 2-3: absmax identical to byte-store epilogue).
template<int FP32_IN>
__global__ __launch_bounds__(256, 2) void mfma_gemm_kernel(
    const void* __restrict__ Xv, const float* __restrict__ scale,
    const ushort* __restrict__ Wt, unsigned char* __restrict__ Y)
{
    int t = threadIdx.x;
    int wv = t >> 6, lane = t & 63;
    int m = lane & 15, q = lane >> 4;
    int tile = blockIdx.x * 4 + wv;
    if (tile >= (N_NODES >> 4)) return;         // 3125 tiles (exact)

    short8 B[8][4];
    #pragma unroll
    for (int cb = 0; cb < 8; ++cb)
        #pragma unroll
        for (int kb = 0; kb < 4; ++kb)
            B[cb][kb] = *(const short8*)&Wt[(size_t)(cb * 16 + m) * 128 + kb * 32 + q * 8];

    int row = tile * 16 + m;
    short8 a[4];
    if (FP32_IN) {
        const float* X = (const float*)Xv;
        float s = scale[row];
        #pragma unroll
        for (int kb = 0; kb < 4; ++kb) {
            const float* p = X + (size_t)row * 128 + kb * 32 + q * 8;
            float4 f0 = *(const float4*)p;
            float4 f1 = *(const float4*)(p + 4);
            short8 av;
            av[0] = (short)f2b(f0.x * s); av[1] = (short)f2b(f0.y * s);
            av[2] = (short)f2b(f0.z * s); av[3] = (short)f2b(f0.w * s);
            av[4] = (short)f2b(f1.x * s); av[5] = (short)f2b(f1.y * s);
            av[6] = (short)f2b(f1.z * s); av[7] = (short)f2b(f1.w * s);
            a[kb] = av;
        }
    } else {
        const ushort* X = (const ushort*)Xv;
        #pragma unroll
        for (int kb = 0; kb < 4; ++kb)
            a[kb] = *(const short8*)(X + (size_t)row * 128 + kb * 32 + q * 8);
    }
    floatx4 acc[8] = {};
    #pragma unroll
    for (int cb = 0; cb < 8; ++cb)
        #pragma unroll
        for (int kb = 0; kb < 4; ++kb)
            acc[cb] = __builtin_amdgcn_mfma_f32_16x16x32_bf16(B[cb][kb], a[kb], acc[cb], 0, 0, 0);

    // swapped D layout: out row = tile*16 + m, cols = cb*16 + q*4 + {0..3}
    unsigned char* yr = Y + (size_t)row * 128;
    #pragma unroll
    for (int cb = 0; cb < 8; ++cb) {
        int lo = __builtin_amdgcn_cvt_pk_fp8_f32(acc[cb][0], acc[cb][1], 0, false);
        int pk = __builtin_amdgcn_cvt_pk_fp8_f32(acc[cb][2], acc[cb][3], lo, true);
        *(unsigned*)(yr + cb * 16 + q * 4) = (unsigned)pk;
    }
}

// ================= K5/K7: SpMM (fp8 gather, ELL): one wave per dst node ========
// Round-0 proven form: 16 lanes x 8 B per source row -> 4 rows (1 cache line
// each) per vmem instruction, predicated step-4 loop, single pass per layer.
// NEW vs round 0: __launch_bounds__(256, 8) pins 8 waves/SIMD (VGPR <= 64) for
// maximum latency hiding on the gather.
__global__ __launch_bounds__(256, 8) void spmm_fp8_kernel(
    const unsigned char* __restrict__ H, const int* __restrict__ in_deg,
    const ushort* __restrict__ slot, const float* __restrict__ norm_dst,
    const float* __restrict__ norm_src, const float* __restrict__ bias,
    ushort* __restrict__ Y, int relu_scale)
{
    int w = (blockIdx.x * blockDim.x + threadIdx.x) >> 6;
    int lane = threadIdx.x & 63;
    if (w >= N_NODES) return;
    int cnt = min(in_deg[w], MAXDEG);
    const ushort* lst = slot + (size_t)w * MAXDEG;
    int g = lane >> 4;            // row-group 0..3
    int c8 = (lane & 15) * 8;     // fp8 col base (8 cols = 8 B)
    int myslot = lst[lane];       // whole slot row staged across the wave
    float acc[8] = {};
    for (int e = 0; e < cnt; e += 4) {
        int idx = e + g;
        bool ok = idx < cnt;
        int s = __shfl(myslot, ok ? idx : 0, 64);
        if (ok) {
            uint2 v = *(const uint2*)&H[(size_t)s * 128 + c8];
            floatx2 p01 = __builtin_amdgcn_cvt_pk_f32_fp8((int)v.x, false);
            floatx2 p23 = __builtin_amdgcn_cvt_pk_f32_fp8((int)v.x, true);
            floatx2 p45 = __builtin_amdgcn_cvt_pk_f32_fp8((int)v.y, false);
            floatx2 p67 = __builtin_amdgcn_cvt_pk_f32_fp8((int)v.y, true);
            acc[0] += p01.x; acc[1] += p01.y;
            acc[2] += p23.x; acc[3] += p23.y;
            acc[4] += p45.x; acc[5] += p45.y;
            acc[6] += p67.x; acc[7] += p67.y;
        }
    }
    #pragma unroll
    for (int j = 0; j < 8; ++j) {
        acc[j] += __shfl_xor(acc[j], 16, 64);
        acc[j] += __shfl_xor(acc[j], 32, 64);
    }
    float ndv = norm_dst[w];
    float4 b0 = *(const float4*)&bias[c8];
    float4 b1 = *(const float4*)&bias[c8 + 4];
    float r[8];
    r[0] = acc[0] * ndv + b0.x; r[1] = acc[1] * ndv + b0.y;
    r[2] = acc[2] * ndv + b0.z; r[3] = acc[3] * ndv + b0.w;
    r[4] = acc[4] * ndv + b1.x; r[5] = acc[5] * ndv + b1.y;
    r[6] = acc[6] * ndv + b1.z; r[7] = acc[7] * ndv + b1.w;
    if (relu_scale) {
        float nsv = norm_src[w];
        #pragma unroll
        for (int j = 0; j < 8; ++j) r[j] = fmaxf(r[j], 0.f) * nsv;
    }
    if (lane < 16) {
        uint4 o;
        o.x = (unsigned)f2b(r[0]) | ((unsigned)f2b(r[1]) << 16);
        o.y = (unsigned)f2b(r[2]) | ((unsigned)f2b(r[3]) << 16);
        o.z = (unsigned)f2b(r[4]) | ((unsigned)f2b(r[5]) << 16);
        o.w = (unsigned)f2b(r[6]) | ((unsigned)f2b(r[7]) << 16);
        *(uint4*)&Y[(size_t)w * 128 + c8] = o;
    }
}

// ================= K8: pooling -> per-block partials (no atomics, no memset) ====
__global__ __launch_bounds__(256) void pool_kernel(
    const ushort* __restrict__ H, const int* __restrict__ start,
    float* __restrict__ part)
{
    __shared__ float red[128];
    int t = threadIdx.x;
    int g = blockIdx.x >> 5, j = blockIdx.x & 31;
    int beg0 = start[g], len = start[g + 1] - beg0;
    int sbeg = beg0 + (int)(((long long)len * j) >> 5);
    int send = beg0 + (int)(((long long)len * (j + 1)) >> 5);
    int wv = t >> 6, lane = t & 63;
    int rg = lane >> 4;
    int c8 = (lane & 15) * 8;
    float acc[8] = {};
    for (int v = sbeg + wv * 4 + rg; v < send; v += 16) {
        uint4 u = *(const uint4*)&H[(size_t)v * 128 + c8];
        acc[0] += b2f(u.x & 0xffff); acc[1] += b2f(u.x >> 16);
        acc[2] += b2f(u.y & 0xffff); acc[3] += b2f(u.y >> 16);
        acc[4] += b2f(u.z & 0xffff); acc[5] += b2f(u.z >> 16);
        acc[6] += b2f(u.w & 0xffff); acc[7] += b2f(u.w >> 16);
    }
    #pragma unroll
    for (int k = 0; k < 8; ++k) {
        acc[k] += __shfl_xor(acc[k], 16, 64);
        acc[k] += __shfl_xor(acc[k], 32, 64);
    }
    if (t < 128) red[t] = 0.f;
    __syncthreads();
    if (lane < 16) {
        #pragma unroll
        for (int k = 0; k < 8; ++k) atomicAdd(&red[c8 + k], acc[k]);
    }
    __syncthreads();
    if (t < 128) part[(size_t)blockIdx.x * 128 + t] = red[t];
}

// ================= K9: head: out[8,64] = (Σpart/cnt) @ Wl + bl ==================
__global__ __launch_bounds__(512) void head_kernel(
    const float* __restrict__ part, const int* __restrict__ start,
    const float* __restrict__ Wl, const float* __restrict__ bl,
    float* __restrict__ out)
{
    __shared__ float means[N_GRAPHS * 128];
    int t = threadIdx.x;
    for (int i = t; i < N_GRAPHS * 128; i += 512) {
        int g = i >> 7, k = i & 127;
        float s = 0.f;
        #pragma unroll 8
        for (int j = 0; j < 32; ++j) s += part[(size_t)(g * 32 + j) * 128 + k];
        float cnt = (float)(start[g + 1] - start[g]);
        means[i] = s / fmaxf(cnt, 1.f);
    }
    __syncthreads();
    int g = t >> 6, c = t & 63;
    float acc = bl[c];
    #pragma unroll 8
    for (int k = 0; k < 128; ++k)
        acc = fmaf(means[g * 128 + k], Wl[k * 64 + c], acc);
    out[g * 64 + c] = acc;
}

extern "C" void kernel_launch(void* const* d_in, const int* in_sizes, int n_in,
                              void* d_out, int out_size, void* d_ws, size_t ws_size,
                              hipStream_t stream) {
    const float* x   = (const float*)d_in[0];
    const float* W1  = (const float*)d_in[1];
    const float* b1  = (const float*)d_in[2];
    const float* W2  = (const float*)d_in[3];
    const float* b2  = (const float*)d_in[4];
    const float* Wl  = (const float*)d_in[5];
    const float* bl  = (const float*)d_in[6];
    const int*   src = (const int*)d_in[7];
    const int*   dst = (const int*)d_in[8];
    const int*   gid = (const int*)d_in[9];

    const int n = N_NODES;

    char* ws = (char*)d_ws;
    size_t off = 0;
    auto alloc = [&](size_t bytes) { size_t o = off; off += (bytes + 255) & ~(size_t)255; return o; };
    unsigned char* hA = (unsigned char*)(ws + alloc((size_t)n * 128));     // gemm out (fp8)
    ushort* hB        = (ushort*)(ws + alloc((size_t)n * 128 * 2));        // spmm out (bf16)
    ushort* slot      = (ushort*)(ws + alloc((size_t)n * MAXDEG * 2));     // ELL src lists
    ushort* counts_in = (ushort*)(ws + alloc((size_t)NCHUNK * n * 2));
    ushort* counts_out= (ushort*)(ws + alloc((size_t)NCHUNK * n * 2));
    ushort* basev     = (ushort*)(ws + alloc((size_t)NCHUNK * n * 2));
    float* norm_src   = (float*) (ws + alloc((size_t)n * 4));
    float* norm_dst   = (float*) (ws + alloc((size_t)n * 4));
    int*   in_deg     = (int*)   (ws + alloc((size_t)n * 4));
    int*   startb     = (int*)   (ws + alloc((size_t)(N_GRAPHS + 1) * 4));
    ushort* Wt1       = (ushort*)(ws + alloc((size_t)128 * 128 * 2));
    ushort* Wt2       = (ushort*)(ws + alloc((size_t)128 * 128 * 2));
    float* part       = (float*) (ws + alloc((size_t)N_GRAPHS * 32 * 128 * 4));

    int spmm_blocks = (n + 3) / 4;
    int gemm_blocks = ((n >> 4) + 3) / 4;       // 1 tile/wave, 4 waves/block

    // K1: count ∪ wt_convert ∪ bounds (round-0 form, no slot-fill)
    prep_kernel<<<321, 1024, 0, stream>>>(src, dst, W1, W2, gid,
                                          counts_in, counts_out, Wt1, Wt2, startb);
    // K2: scan
    scan_kernel<<<(n + 255) / 256, 256, 0, stream>>>(counts_in, counts_out, basev,
                                                     in_deg, norm_src, norm_dst);
    // K3: scatter (LDS-seeded bases)
    scatter_kernel<<<NRANGE * NCHUNK, 1024, 0, stream>>>(src, dst, basev, slot);
    // K4: gemm1  (hA = fp8((x*ns) @ W1))
    mfma_gemm_kernel<1><<<gemm_blocks, 256, 0, stream>>>(x, norm_src, Wt1, hA);
    // K5: spmm1  (hB = bf16(relu(agg*nd + b1) * ns))
    spmm_fp8_kernel<<<spmm_blocks, 256, 0, stream>>>(hA, in_deg, slot, norm_dst,
                                                     norm_src, b1, hB, 1);
    // K6: gemm2  (hA = fp8(hB @ W2))
    mfma_gemm_kernel<0><<<gemm_blocks, 256, 0, stream>>>(hB, nullptr, Wt2, hA);
    // K7: spmm2  (hB = bf16(agg*nd + b2))
    spmm_fp8_kernel<<<spmm_blocks, 256, 0, stream>>>(hA, in_deg, slot, norm_dst,
                                                     nullptr, b2, hB, 0);
    // K8: pool partials
    pool_kernel<<<N_GRAPHS * 32, 256, 0, stream>>>(hB, startb, part);
    // K9: head
    head_kernel<<<1, 512, 0, stream>>>(part, startb, Wl, bl, (float*)d_out);
}

// Round 5
// 199.708 us; speedup vs baseline: 1.2447x; 1.1445x over previous
//
#include <hip/hip_runtime.h>
#include <hip/hip_bf16.h>

#define N_NODES 50000
#define N_EDGES 800000
#define N_GRAPHS 8
#define MAXDEG 64
#define NRANGE 4
#define NCHUNK 64
#define RSZ (N_NODES / NRANGE)      // 12500 nodes per range
#define CHE (N_EDGES / NCHUNK)      // 12500 edges per chunk

typedef __attribute__((ext_vector_type(8))) short short8;
typedef __attribute__((ext_vector_type(4))) float floatx4;
typedef __attribute__((ext_vector_type(2))) float floatx2;

static __device__ __forceinline__ ushort f2b(float f) {
    union { float f; unsigned u; } v; v.f = f;
    return (ushort)((v.u + 0x7FFF + ((v.u >> 16) & 1)) >> 16);  // RNE
}
static __device__ __forceinline__ float b2f(unsigned u) {
    union { unsigned u; float f; } v; v.u = u << 16;
    return v.f;
}
// fp8 e4m3 (OCP on gfx950) encode via hw packed convert
static __device__ __forceinline__ unsigned char f2q(float f) {
    int p = __builtin_amdgcn_cvt_pk_fp8_f32(f, f, 0, false);
    return (unsigned char)(p & 0xff);
}

// ================= K1: prep = count ∪ wt_convert ∪ bound (round-0 verbatim) ====
__global__ __launch_bounds__(1024) void prep_kernel(
    const int* __restrict__ src, const int* __restrict__ dst,
    const float* __restrict__ W1, const float* __restrict__ W2,
    const int* __restrict__ gid,
    ushort* __restrict__ counts_in, ushort* __restrict__ counts_out,
    ushort* __restrict__ Wt1, ushort* __restrict__ Wt2,
    int* __restrict__ start)
{
    int b = blockIdx.x, t = threadIdx.x;
    if (b < 256) {
        __shared__ unsigned h[RSZ];   // [0,RSZ/2) in-hist, [RSZ/2,RSZ) out-hist (packed 2x16)
        int c = b & (NCHUNK - 1), r = b >> 6;
        int lo = r * RSZ;
        for (int j = t; j < RSZ; j += 1024) h[j] = 0;
        __syncthreads();
        int ebeg = c * CHE, eend = ebeg + CHE;
        for (int i = ebeg + t; i < eend; i += 1024) {
            int s = src[i], d = dst[i];
            unsigned ds = (unsigned)(d - lo);
            if (ds < RSZ) atomicAdd(&h[ds >> 1], 1u << ((ds & 1) * 16));
            unsigned ss = (unsigned)(s - lo);
            if (ss < RSZ) atomicAdd(&h[(RSZ / 2) + (ss >> 1)], 1u << ((ss & 1) * 16));
        }
        __syncthreads();
        unsigned* ci = (unsigned*)(counts_in  + (size_t)c * N_NODES + lo);
        unsigned* co = (unsigned*)(counts_out + (size_t)c * N_NODES + lo);
        for (int j = t; j < RSZ / 2; j += 1024) {
            ci[j] = h[j];
            co[j] = h[(RSZ / 2) + j];
        }
    } else if (b < 272) {
        int i = (b - 256) * 1024 + t;          // 16384 elems
        int c = i >> 7, k = i & 127;
        Wt1[i] = f2b(W1[k * 128 + c]);
        Wt2[i] = f2b(W2[k * 128 + c]);
    } else {
        int i = (b - 272) * 1024 + t;
        if (i < N_NODES) {
            int g = gid[i];
            int gp = (i == 0) ? -1 : gid[i - 1];
            for (int k = gp + 1; k <= g; ++k) start[k] = i;    // unique writer per k
            if (i == N_NODES - 1)
                for (int k = g + 1; k <= N_GRAPHS; ++k) start[k] = N_NODES;
        }
    }
}

// ================= K2: scan chunk counts -> degrees, norms, slot bases ==========
__global__ __launch_bounds__(256) void scan_kernel(
    const ushort* __restrict__ counts_in, const ushort* __restrict__ counts_out,
    ushort* __restrict__ base, int* __restrict__ in_deg,
    float* __restrict__ ns, float* __restrict__ nd)
{
    int v = blockIdx.x * 256 + threadIdx.x;
    if (v >= N_NODES) return;
    unsigned od = 0;
    #pragma unroll 8
    for (int c = 0; c < NCHUNK; ++c) od += counts_out[(size_t)c * N_NODES + v];
    unsigned run = 0;
    #pragma unroll 8
    for (int c = 0; c < NCHUNK; ++c) {
        base[(size_t)c * N_NODES + v] = (ushort)run;
        run += counts_in[(size_t)c * N_NODES + v];
    }
    in_deg[v] = (int)run;
    ns[v] = rsqrtf(fmaxf((float)od, 1.f));
    nd[v] = rsqrtf(fmaxf((float)run, 1.f));
}

// ================= K3: scatter into ELL slots using LDS-seeded bases ===========
__global__ __launch_bounds__(1024) void scatter_kernel(
    const int* __restrict__ src, const int* __restrict__ dst,
    const ushort* __restrict__ base, ushort* __restrict__ slot)
{
    __shared__ unsigned h[RSZ / 2];   // packed 2x16 running positions
    int t = threadIdx.x;
    int c = blockIdx.x & (NCHUNK - 1), r = blockIdx.x >> 6;
    int lo = r * RSZ;
    const unsigned* bp = (const unsigned*)(base + (size_t)c * N_NODES + lo);
    for (int j = t; j < RSZ / 2; j += 1024) h[j] = bp[j];
    __syncthreads();
    int ebeg = c * CHE, eend = ebeg + CHE;
    for (int i = ebeg + t; i < eend; i += 1024) {
        int d = dst[i];
        unsigned ds = (unsigned)(d - lo);
        if (ds < RSZ) {
            int sh = (ds & 1) * 16;
            unsigned old = atomicAdd(&h[ds >> 1], 1u << sh);
            unsigned pos = (old >> sh) & 0xffff;
            if (pos < MAXDEG) slot[(size_t)d * MAXDEG + pos] = (ushort)src[i];
        }
    }
}

// ================= K4/K6: persistent MFMA GEMM (round-0 verbatim) ==============
template<int FP32_IN>
__global__ __launch_bounds__(256, 2) void mfma_gemm_kernel(
    const void* __restrict__ Xv, const float* __restrict__ scale,
    const ushort* __restrict__ Wt, unsigned char* __restrict__ Y, int n)
{
    int t = threadIdx.x;
    int wv = t >> 6, lane = t & 63;
    int m = lane & 15, q = lane >> 4;
    short8 B[8][4];
    #pragma unroll
    for (int cb = 0; cb < 8; ++cb)
        #pragma unroll
        for (int kb = 0; kb < 4; ++kb)
            B[cb][kb] = *(const short8*)&Wt[(size_t)(cb * 16 + m) * 128 + kb * 32 + q * 8];

    int ntile = n >> 4;                      // 3125 (exact)
    int gw = blockIdx.x * 4 + wv;            // 2048 waves
    for (int tile = gw; tile < ntile; tile += 2048) {
        int row = tile * 16 + m;
        short8 a[4];
        if (FP32_IN) {
            const float* X = (const float*)Xv;
            float s = scale[row];
            #pragma unroll
            for (int kb = 0; kb < 4; ++kb) {
                const float* p = X + (size_t)row * 128 + kb * 32 + q * 8;
                float4 f0 = *(const float4*)p;
                float4 f1 = *(const float4*)(p + 4);
                short8 av;
                av[0] = (short)f2b(f0.x * s); av[1] = (short)f2b(f0.y * s);
                av[2] = (short)f2b(f0.z * s); av[3] = (short)f2b(f0.w * s);
                av[4] = (short)f2b(f1.x * s); av[5] = (short)f2b(f1.y * s);
                av[6] = (short)f2b(f1.z * s); av[7] = (short)f2b(f1.w * s);
                a[kb] = av;
            }
        } else {
            const ushort* X = (const ushort*)Xv;
            #pragma unroll
            for (int kb = 0; kb < 4; ++kb)
                a[kb] = *(const short8*)(X + (size_t)row * 128 + kb * 32 + q * 8);
        }
        floatx4 acc[8] = {};
        #pragma unroll
        for (int cb = 0; cb < 8; ++cb)
            #pragma unroll
            for (int kb = 0; kb < 4; ++kb)
                acc[cb] = __builtin_amdgcn_mfma_f32_16x16x32_bf16(a[kb], B[cb][kb], acc[cb], 0, 0, 0);
        // C/D layout: col = cb*16 + m, row = tile*16 + q*4 + r
        int rowbase = tile * 16 + q * 4;
        #pragma unroll
        for (int cb = 0; cb < 8; ++cb)
            #pragma unroll
            for (int r = 0; r < 4; ++r)
                Y[(size_t)(rowbase + r) * 128 + cb * 16 + m] = f2q(acc[cb][r]);
    }
}

// ================= K5/K7: SpMM — 8 nodes per wave (8 lanes x 16 B per node) ====
// Theory (R3 measurement): SpMM cost ~ wave count x per-wave fixed work.
// This cuts waves 50000 -> 6250 and kills the cross-lane reduce entirely:
// lane (g,j) owns node (wid*8+g), cols j*16..j*16+15. Inner loop is
// wave-uniform to max-deg-of-8 with per-group predication; slots staged
// 8-at-a-time (coalesced); unroll-8 issues up to 8 independent 16-B gathers.
__global__ __launch_bounds__(256) void spmm_fp8_kernel(
    const unsigned char* __restrict__ H, const int* __restrict__ in_deg,
    const ushort* __restrict__ slot, const float* __restrict__ norm_dst,
    const float* __restrict__ norm_src, const float* __restrict__ bias,
    ushort* __restrict__ Y, int relu_scale)
{
    int wid = (blockIdx.x * blockDim.x + threadIdx.x) >> 6;
    if (wid >= N_NODES / 8) return;            // 6250 waves exact
    int lane = threadIdx.x & 63;
    int g = lane >> 3;            // node group 0..7
    int j = lane & 7;             // 16-B chunk of the 128-B fp8 row
    int node = wid * 8 + g;
    int cnt = min(in_deg[node], MAXDEG);       // uniform within group
    float ndv = norm_dst[node];
    const ushort* lst = slot + (size_t)node * MAXDEG;

    // wave-uniform loop bound: max cnt over the 8 groups
    int cm = cnt;
    cm = max(cm, __shfl_xor(cm, 8, 64));
    cm = max(cm, __shfl_xor(cm, 16, 64));
    cm = max(cm, __shfl_xor(cm, 32, 64));

    float acc[16] = {};
    for (int e0 = 0; e0 < cm; e0 += 8) {
        int sl = lst[e0 + j];                  // stage 8 slots (coalesced 16 B/group)
        #pragma unroll
        for (int k = 0; k < 8; ++k) {
            if (e0 + k < cnt) {
                int s = __shfl(sl, g * 8 + k, 64);   // slot of my group's node, pos e0+k
                uint4 v = *(const uint4*)&H[(size_t)s * 128 + j * 16];
                floatx2 p;
                p = __builtin_amdgcn_cvt_pk_f32_fp8((int)v.x, false); acc[0] += p.x;  acc[1] += p.y;
                p = __builtin_amdgcn_cvt_pk_f32_fp8((int)v.x, true);  acc[2] += p.x;  acc[3] += p.y;
                p = __builtin_amdgcn_cvt_pk_f32_fp8((int)v.y, false); acc[4] += p.x;  acc[5] += p.y;
                p = __builtin_amdgcn_cvt_pk_f32_fp8((int)v.y, true);  acc[6] += p.x;  acc[7] += p.y;
                p = __builtin_amdgcn_cvt_pk_f32_fp8((int)v.z, false); acc[8] += p.x;  acc[9] += p.y;
                p = __builtin_amdgcn_cvt_pk_f32_fp8((int)v.z, true);  acc[10] += p.x; acc[11] += p.y;
                p = __builtin_amdgcn_cvt_pk_f32_fp8((int)v.w, false); acc[12] += p.x; acc[13] += p.y;
                p = __builtin_amdgcn_cvt_pk_f32_fp8((int)v.w, true);  acc[14] += p.x; acc[15] += p.y;
            }
        }
    }

    int c16 = j * 16;
    float r[16];
    #pragma unroll
    for (int u = 0; u < 4; ++u) {
        float4 bv = *(const float4*)&bias[c16 + u * 4];
        r[u * 4 + 0] = acc[u * 4 + 0] * ndv + bv.x;
        r[u * 4 + 1] = acc[u * 4 + 1] * ndv + bv.y;
        r[u * 4 + 2] = acc[u * 4 + 2] * ndv + bv.z;
        r[u * 4 + 3] = acc[u * 4 + 3] * ndv + bv.w;
    }
    if (relu_scale) {
        float nsv = norm_src[node];
        #pragma unroll
        for (int u = 0; u < 16; ++u) r[u] = fmaxf(r[u], 0.f) * nsv;
    }
    uint4 o0, o1;
    o0.x = (unsigned)f2b(r[0])  | ((unsigned)f2b(r[1])  << 16);
    o0.y = (unsigned)f2b(r[2])  | ((unsigned)f2b(r[3])  << 16);
    o0.z = (unsigned)f2b(r[4])  | ((unsigned)f2b(r[5])  << 16);
    o0.w = (unsigned)f2b(r[6])  | ((unsigned)f2b(r[7])  << 16);
    o1.x = (unsigned)f2b(r[8])  | ((unsigned)f2b(r[9])  << 16);
    o1.y = (unsigned)f2b(r[10]) | ((unsigned)f2b(r[11]) << 16);
    o1.z = (unsigned)f2b(r[12]) | ((unsigned)f2b(r[13]) << 16);
    o1.w = (unsigned)f2b(r[14]) | ((unsigned)f2b(r[15]) << 16);
    uint4* yp = (uint4*)&Y[(size_t)node * 128 + c16];
    yp[0] = o0;
    yp[1] = o1;
}

// ================= K8: pooling -> per-block partials (round-0 verbatim) ========
__global__ __launch_bounds__(256) void pool_kernel(
    const ushort* __restrict__ H, const int* __restrict__ start,
    float* __restrict__ part)
{
    __shared__ float red[128];
    int t = threadIdx.x;
    int g = blockIdx.x >> 5, j = blockIdx.x & 31;
    int beg0 = start[g], len = start[g + 1] - beg0;
    int sbeg = beg0 + (int)(((long long)len * j) >> 5);
    int send = beg0 + (int)(((long long)len * (j + 1)) >> 5);
    int wv = t >> 6, lane = t & 63;
    int rg = lane >> 4;
    int c8 = (lane & 15) * 8;
    float acc[8] = {};
    for (int v = sbeg + wv * 4 + rg; v < send; v += 16) {
        uint4 u = *(const uint4*)&H[(size_t)v * 128 + c8];
        acc[0] += b2f(u.x & 0xffff); acc[1] += b2f(u.x >> 16);
        acc[2] += b2f(u.y & 0xffff); acc[3] += b2f(u.y >> 16);
        acc[4] += b2f(u.z & 0xffff); acc[5] += b2f(u.z >> 16);
        acc[6] += b2f(u.w & 0xffff); acc[7] += b2f(u.w >> 16);
    }
    #pragma unroll
    for (int k = 0; k < 8; ++k) {
        acc[k] += __shfl_xor(acc[k], 16, 64);
        acc[k] += __shfl_xor(acc[k], 32, 64);
    }
    if (t < 128) red[t] = 0.f;
    __syncthreads();
    if (lane < 16) {
        #pragma unroll
        for (int k = 0; k < 8; ++k) atomicAdd(&red[c8 + k], acc[k]);
    }
    __syncthreads();
    if (t < 128) part[(size_t)blockIdx.x * 128 + t] = red[t];
}

// ================= K9: head (round-0 verbatim) =================================
__global__ __launch_bounds__(512) void head_kernel(
    const float* __restrict__ part, const int* __restrict__ start,
    const float* __restrict__ Wl, const float* __restrict__ bl,
    float* __restrict__ out)
{
    __shared__ float means[N_GRAPHS * 128];
    int t = threadIdx.x;
    for (int i = t; i < N_GRAPHS * 128; i += 512) {
        int g = i >> 7, k = i & 127;
        float s = 0.f;
        #pragma unroll 8
        for (int j = 0; j < 32; ++j) s += part[(size_t)(g * 32 + j) * 128 + k];
        float cnt = (float)(start[g + 1] - start[g]);
        means[i] = s / fmaxf(cnt, 1.f);
    }
    __syncthreads();
    int g = t >> 6, c = t & 63;
    float acc = bl[c];
    #pragma unroll 8
    for (int k = 0; k < 128; ++k)
        acc = fmaf(means[g * 128 + k], Wl[k * 64 + c], acc);
    out[g * 64 + c] = acc;
}

extern "C" void kernel_launch(void* const* d_in, const int* in_sizes, int n_in,
                              void* d_out, int out_size, void* d_ws, size_t ws_size,
                              hipStream_t stream) {
    const float* x   = (const float*)d_in[0];
    const float* W1  = (const float*)d_in[1];
    const float* b1  = (const float*)d_in[2];
    const float* W2  = (const float*)d_in[3];
    const float* b2  = (const float*)d_in[4];
    const float* Wl  = (const float*)d_in[5];
    const float* bl  = (const float*)d_in[6];
    const int*   src = (const int*)d_in[7];
    const int*   dst = (const int*)d_in[8];
    const int*   gid = (const int*)d_in[9];

    const int n = N_NODES;

    char* ws = (char*)d_ws;
    size_t off = 0;
    auto alloc = [&](size_t bytes) { size_t o = off; off += (bytes + 255) & ~(size_t)255; return o; };
    unsigned char* hA = (unsigned char*)(ws + alloc((size_t)n * 128));     // gemm out (fp8)
    ushort* hB        = (ushort*)(ws + alloc((size_t)n * 128 * 2));        // spmm out (bf16)
    ushort* slot      = (ushort*)(ws + alloc((size_t)n * MAXDEG * 2));     // ELL src lists
    ushort* counts_in = (ushort*)(ws + alloc((size_t)NCHUNK * n * 2));
    ushort* counts_out= (ushort*)(ws + alloc((size_t)NCHUNK * n * 2));
    ushort* basev     = (ushort*)(ws + alloc((size_t)NCHUNK * n * 2));
    float* norm_src   = (float*) (ws + alloc((size_t)n * 4));
    float* norm_dst   = (float*) (ws + alloc((size_t)n * 4));
    int*   in_deg     = (int*)   (ws + alloc((size_t)n * 4));
    int*   startb     = (int*)   (ws + alloc((size_t)(N_GRAPHS + 1) * 4));
    ushort* Wt1       = (ushort*)(ws + alloc((size_t)128 * 128 * 2));
    ushort* Wt2       = (ushort*)(ws + alloc((size_t)128 * 128 * 2));
    float* part       = (float*) (ws + alloc((size_t)N_GRAPHS * 32 * 128 * 4));

    int spmm_blocks = (N_NODES / 8 + 3) / 4;    // 6250 waves, 4 waves/block -> 1563

    // K1: count ∪ wt_convert ∪ bounds
    prep_kernel<<<321, 1024, 0, stream>>>(src, dst, W1, W2, gid,
                                          counts_in, counts_out, Wt1, Wt2, startb);
    // K2: scan
    scan_kernel<<<(n + 255) / 256, 256, 0, stream>>>(counts_in, counts_out, basev,
                                                     in_deg, norm_src, norm_dst);
    // K3: scatter (LDS-seeded bases)
    scatter_kernel<<<NRANGE * NCHUNK, 1024, 0, stream>>>(src, dst, basev, slot);
    // K4: gemm1  (hA = fp8((x*ns) @ W1))
    mfma_gemm_kernel<1><<<512, 256, 0, stream>>>(x, norm_src, Wt1, hA, n);
    // K5: spmm1  (hB = bf16(relu(agg*nd + b1) * ns))
    spmm_fp8_kernel<<<spmm_blocks, 256, 0, stream>>>(hA, in_deg, slot, norm_dst,
                                                     norm_src, b1, hB, 1);
    // K6: gemm2  (hA = fp8(hB @ W2))
    mfma_gemm_kernel<0><<<512, 256, 0, stream>>>(hB, nullptr, Wt2, hA, n);
    // K7: spmm2  (hB = bf16(agg*nd + b2))
    spmm_fp8_kernel<<<spmm_blocks, 256, 0, stream>>>(hA, in_deg, slot, norm_dst,
                                                     nullptr, b2, hB, 0);
    // K8: pool partials
    pool_kernel<<<N_GRAPHS * 32, 256, 0, stream>>>(hB, startb, part);
    // K9: head
    head_kernel<<<1, 512, 0, stream>>>(part, startb, Wl, bl, (float*)d_out);
}